// Round 1
// baseline (315.399 us; speedup 1.0000x reference)
//
#include <hip/hip_runtime.h>

typedef _Float16 f16;
typedef _Float16 half8 __attribute__((ext_vector_type(8), may_alias));
typedef _Float16 half4 __attribute__((ext_vector_type(4), may_alias));
typedef float f32x4 __attribute__((ext_vector_type(4), may_alias));

// ---------------------------------------------------------------- helpers
__device__ __forceinline__ void gload_lds16(const f16* g, f16* lds) {
  // async global->LDS, 16B per lane; LDS dest = wave-uniform base + lane*16
  __builtin_amdgcn_global_load_lds(
      (const __attribute__((address_space(1))) void*)g,
      (__attribute__((address_space(3))) void*)lds, 16, 0, 0);
}

// ---------------------------------------------------------------- fp32 -> f16
__global__ __launch_bounds__(256) void cvt_f32_f16(const float* __restrict__ src,
                                                   f16* __restrict__ dst, int n) {
  const int step = gridDim.x * blockDim.x * 4;
  for (int i = (blockIdx.x * blockDim.x + threadIdx.x) * 4; i < n; i += step) {
    float4 v = *(const float4*)(src + i);
    half4 h;
    h[0] = (f16)v.x; h[1] = (f16)v.y; h[2] = (f16)v.z; h[3] = (f16)v.w;
    *(half4*)(dst + i) = h;
  }
}

// ---------------------------------------------------------------- RoPE (in-place, f16)
// interleaved pairs (2i, 2i+1) within each 64-wide head; pos from token_positions
__global__ __launch_bounds__(256) void rope_inplace(f16* __restrict__ X,
                                                    const int* __restrict__ pos,
                                                    int rows, int cols, int S,
                                                    float scale) {
  const int cp = cols >> 1;
  const int total = rows * cp;
  const float kf = -0.41524101186092027f;  // -log2(10000)/32
  const int step = gridDim.x * blockDim.x;
  for (int p = blockIdx.x * blockDim.x + threadIdx.x; p < total; p += step) {
    const int row = p / cp;
    const int pi = p - row * cp;
    const int i = pi & 31;  // pair index within head (Dh=64 -> 32 pairs)
    const float ang = (float)pos[row % S] * exp2f(kf * (float)i);
    float s, c;
    sincosf(ang, &s, &c);
    f16* ptr = X + (size_t)row * cols + (pi << 1);
    const float x1 = (float)ptr[0], x2 = (float)ptr[1];
    ptr[0] = (f16)((x1 * c - x2 * s) * scale);
    ptr[1] = (f16)((x1 * s + x2 * c) * scale);
  }
}

// ---------------------------------------------------------------- GEMM: C = A @ B^T
// A[M][K], B[N][K] f16 row-major; C f32 (OUT_F32=1) or f16 (OUT_F32=0).
// 128x128 tile, BK=32, 4 waves (2x2), 4x4 16x16x32 MFMA frags per wave.
template <int OUT_F32>
__global__ __launch_bounds__(256) void gemm_bt(const f16* __restrict__ A,
                                               const f16* __restrict__ B,
                                               void* __restrict__ Cv,
                                               int M, int N, int K) {
  __shared__ alignas(16) f16 As[128][32];
  __shared__ alignas(16) f16 Bs[128][32];
  const int tid = threadIdx.x;
  const int w = tid >> 6, l = tid & 63;
  const int m0 = blockIdx.y << 7, n0 = blockIdx.x << 7;
  const int wr = (w >> 1) << 6, wc = (w & 1) << 6;
  const int fr = l & 15;             // fragment row (A) / col (B)
  const int fk = (l >> 4) << 3;      // fragment k offset
  const int srow = l >> 2;           // staging: 4 lanes per 32-elem row
  const int scol = (l & 3) << 3;

  f32x4 acc[4][4] = {};

  for (int k0 = 0; k0 < K; k0 += 32) {
#pragma unroll
    for (int c = 0; c < 2; ++c) {
      const int rb = (w * 2 + c) * 16;  // wave-uniform 16-row chunk
      gload_lds16(A + (size_t)(m0 + rb + srow) * K + k0 + scol, &As[rb][0]);
      gload_lds16(B + (size_t)(n0 + rb + srow) * K + k0 + scol, &Bs[rb][0]);
    }
    __syncthreads();
    half8 af[4], bfr[4];
#pragma unroll
    for (int i = 0; i < 4; ++i) af[i] = *(const half8*)&As[wr + i * 16 + fr][fk];
#pragma unroll
    for (int j = 0; j < 4; ++j) bfr[j] = *(const half8*)&Bs[wc + j * 16 + fr][fk];
#pragma unroll
    for (int i = 0; i < 4; ++i)
#pragma unroll
      for (int j = 0; j < 4; ++j)
        acc[i][j] = __builtin_amdgcn_mfma_f32_16x16x32_f16(af[i], bfr[j], acc[i][j], 0, 0, 0);
    __syncthreads();
  }

  const int orow = (l >> 4) << 2;
#pragma unroll
  for (int i = 0; i < 4; ++i) {
#pragma unroll
    for (int j = 0; j < 4; ++j) {
      const int col = n0 + wc + j * 16 + fr;
#pragma unroll
      for (int r = 0; r < 4; ++r) {
        const size_t idx = (size_t)(m0 + wr + i * 16 + orow + r) * N + col;
        if (OUT_F32) ((float*)Cv)[idx] = acc[i][j][r];
        else ((f16*)Cv)[idx] = (f16)acc[i][j][r];
      }
    }
  }
}

// ---------------------------------------------------------------- causal GQA attention
// Q: [B*S][2048] (head-major cols, pre-scaled by 1/8, roped)
// K,V: [B*S][512]; O: [B*S][2048] f16.  QBLK=64 (4 waves x 16 rows), KVBLK=64.
__global__ __launch_bounds__(256) void attn_fwd(const f16* __restrict__ Q,
                                                const f16* __restrict__ K,
                                                const f16* __restrict__ V,
                                                f16* __restrict__ O) {
  const int qt = blockIdx.x;   // q tile (0..15)
  const int h = blockIdx.y;    // q head (0..31)
  const int b = blockIdx.z;    // batch
  const int kvh = h >> 2;      // G=4
  const int tid = threadIdx.x, w = tid >> 6, l = tid & 63;
  const int fr = l & 15;
  const int fk = (l >> 4) << 3;
  const int orow = (l >> 4) << 2;
  const int qbase = qt << 6;

  __shared__ alignas(16) f16 Ks[64][64];
  __shared__ alignas(16) f16 Vt[64][64];   // transposed: Vt[d][kv]
  __shared__ alignas(16) f16 Ps[4][16][64];  // per-wave P staging

  // Q fragments (16 rows x 64 d) held in registers
  const int qrow = qbase + w * 16 + fr;
  const f16* qp = Q + (size_t)(b * 1024 + qrow) * 2048 + h * 64 + fk;
  const half8 aq0 = *(const half8*)qp;
  const half8 aq1 = *(const half8*)(qp + 32);

  float rm[4] = {-3.0e38f, -3.0e38f, -3.0e38f, -3.0e38f};
  float rl[4] = {0.f, 0.f, 0.f, 0.f};
  f32x4 o[4] = {};

  const int srowk = tid >> 3;        // staging: 8 lanes per 64-elem row
  const int scolk = (tid & 7) << 3;

  for (int kt = 0; kt <= qt; ++kt) {
    const int kvbase = kt << 6;
    // ---- stage K (row-major) and V (transposed) into LDS
#pragma unroll
    for (int p = 0; p < 2; ++p) {
      const int row = srowk + p * 32;
      const size_t gro = (size_t)(b * 1024 + kvbase + row) * 512 + kvh * 64 + scolk;
      *(half8*)&Ks[row][scolk] = *(const half8*)(K + gro);
      const half8 vv = *(const half8*)(V + gro);
#pragma unroll
      for (int ii = 0; ii < 8; ++ii) Vt[scolk + ii][row] = vv[ii];
    }
    __syncthreads();

    // ---- S = Q K^T  (16 q-rows x 64 kv-cols per wave)
    f32x4 s4[4] = {};
#pragma unroll
    for (int j = 0; j < 4; ++j) {
      const half8 bk0 = *(const half8*)&Ks[j * 16 + fr][fk];
      const half8 bk1 = *(const half8*)&Ks[j * 16 + fr][32 + fk];
      s4[j] = __builtin_amdgcn_mfma_f32_16x16x32_f16(aq0, bk0, s4[j], 0, 0, 0);
      s4[j] = __builtin_amdgcn_mfma_f32_16x16x32_f16(aq1, bk1, s4[j], 0, 0, 0);
    }

    // ---- causal mask (only the diagonal tile needs it)
    if (kt == qt) {
#pragma unroll
      for (int j = 0; j < 4; ++j) {
        const int col = kvbase + j * 16 + fr;
#pragma unroll
        for (int r = 0; r < 4; ++r)
          if (col > qbase + w * 16 + orow + r) s4[j][r] = -1.0e30f;
      }
    }

    // ---- online softmax: row max + rescale
#pragma unroll
    for (int r = 0; r < 4; ++r) {
      float mx = fmaxf(fmaxf(s4[0][r], s4[1][r]), fmaxf(s4[2][r], s4[3][r]));
#pragma unroll
      for (int off = 8; off >= 1; off >>= 1) mx = fmaxf(mx, __shfl_xor(mx, off));
      const float mn = fmaxf(rm[r], mx);
      const float sf = __expf(rm[r] - mn);
      rl[r] *= sf;
      o[0][r] *= sf; o[1][r] *= sf; o[2][r] *= sf; o[3][r] *= sf;
      rm[r] = mn;
    }

    // ---- P = exp(S - m), stash to LDS (wave-private) for A-operand relayout
    float ps[4] = {0.f, 0.f, 0.f, 0.f};
#pragma unroll
    for (int j = 0; j < 4; ++j) {
#pragma unroll
      for (int r = 0; r < 4; ++r) {
        const float p = __expf(s4[j][r] - rm[r]);
        ps[r] += p;
        Ps[w][orow + r][j * 16 + fr] = (f16)p;
      }
    }
#pragma unroll
    for (int r = 0; r < 4; ++r) {
      float t = ps[r];
#pragma unroll
      for (int off = 8; off >= 1; off >>= 1) t += __shfl_xor(t, off);
      rl[r] += t;
    }

    // ---- O += P @ V
#pragma unroll
    for (int kv2 = 0; kv2 < 2; ++kv2) {
      const half8 ap = *(const half8*)&Ps[w][fr][kv2 * 32 + fk];
#pragma unroll
      for (int j = 0; j < 4; ++j) {
        const half8 bv = *(const half8*)&Vt[j * 16 + fr][kv2 * 32 + fk];
        o[j] = __builtin_amdgcn_mfma_f32_16x16x32_f16(ap, bv, o[j], 0, 0, 0);
      }
    }
    __syncthreads();
  }

  // ---- normalize + write (b,s) row, head-major cols
#pragma unroll
  for (int j = 0; j < 4; ++j) {
#pragma unroll
    for (int r = 0; r < 4; ++r) {
      const int row = qbase + w * 16 + orow + r;
      O[(size_t)(b * 1024 + row) * 2048 + h * 64 + j * 16 + fr] = (f16)(o[j][r] / rl[r]);
    }
  }
}

// ---------------------------------------------------------------- launch
extern "C" void kernel_launch(void* const* d_in, const int* in_sizes, int n_in,
                              void* d_out, int out_size, void* d_ws, size_t ws_size,
                              hipStream_t stream) {
  const float* X = (const float*)d_in[0];
  const int* tokpos = (const int*)d_in[1];
  const float* qw = (const float*)d_in[2];
  const float* kw = (const float*)d_in[3];
  const float* vw = (const float*)d_in[4];
  const float* ow = (const float*)d_in[5];

  constexpr int B = 2, S = 1024, D = 2048, DKV = 512, H = 32;
  constexpr int M = B * S;  // 2048

  char* ws = (char*)d_ws;
  f16* Xh  = (f16*)(ws);                      // 8 MiB
  f16* qwh = (f16*)(ws + (8u << 20));         // 8 MiB
  f16* kwh = (f16*)(ws + (16u << 20));        // 2 MiB
  f16* vwh = (f16*)(ws + (18u << 20));        // 2 MiB
  f16* owh = (f16*)(ws + (20u << 20));        // 8 MiB
  f16* Qh  = (f16*)(ws + (28u << 20));        // 8 MiB
  f16* Kh  = (f16*)(ws + (36u << 20));        // 2 MiB
  f16* Vh  = (f16*)(ws + (38u << 20));        // 2 MiB
  f16* Ah  = (f16*)(ws + (40u << 20));        // 8 MiB -> 48 MiB total

  // fp32 -> f16
  cvt_f32_f16<<<2048, 256, 0, stream>>>(X, Xh, M * D);
  cvt_f32_f16<<<2048, 256, 0, stream>>>(qw, qwh, D * D);
  cvt_f32_f16<<<1024, 256, 0, stream>>>(kw, kwh, DKV * D);
  cvt_f32_f16<<<1024, 256, 0, stream>>>(vw, vwh, DKV * D);
  cvt_f32_f16<<<2048, 256, 0, stream>>>(ow, owh, D * D);

  // projections (C = X @ W^T)
  gemm_bt<0><<<dim3(D / 128, M / 128), 256, 0, stream>>>(Xh, qwh, Qh, M, D, D);
  gemm_bt<0><<<dim3(DKV / 128, M / 128), 256, 0, stream>>>(Xh, kwh, Kh, M, DKV, D);
  gemm_bt<0><<<dim3(DKV / 128, M / 128), 256, 0, stream>>>(Xh, vwh, Vh, M, DKV, D);

  // RoPE in place (Q also absorbs the 1/sqrt(Dh)=0.125 score scale)
  rope_inplace<<<2048, 256, 0, stream>>>(Qh, tokpos, M, D, S, 0.125f);
  rope_inplace<<<512, 256, 0, stream>>>(Kh, tokpos, M, DKV, S, 1.0f);

  // causal GQA attention
  attn_fwd<<<dim3(S / 64, H, B), 256, 0, stream>>>(Qh, Kh, Vh, Ah);

  // output projection -> fp32 d_out
  gemm_bt<1><<<dim3(D / 128, M / 128), 256, 0, stream>>>(Ah, owh, d_out, M, D, D);
}

// Round 2
// 172.563 us; speedup vs baseline: 1.8277x; 1.8277x over previous
//
#include <hip/hip_runtime.h>

typedef _Float16 f16;
typedef _Float16 half8 __attribute__((ext_vector_type(8), may_alias));
typedef _Float16 half4 __attribute__((ext_vector_type(4), may_alias));
typedef float f32x4 __attribute__((ext_vector_type(4), may_alias));

// ---------------------------------------------------------------- helpers
__device__ __forceinline__ void gload_lds16(const f16* g, f16* lds) {
  __builtin_amdgcn_global_load_lds(
      (const __attribute__((address_space(1))) void*)g,
      (__attribute__((address_space(3))) void*)lds, 16, 0, 0);
}

// ---------------------------------------------------------------- fp32 -> f16
__global__ __launch_bounds__(256) void cvt_f32_f16(const float* __restrict__ src,
                                                   f16* __restrict__ dst, int n) {
  const int step = gridDim.x * blockDim.x * 4;
  for (int i = (blockIdx.x * blockDim.x + threadIdx.x) * 4; i < n; i += step) {
    float4 v = *(const float4*)(src + i);
    half4 h;
    h[0] = (f16)v.x; h[1] = (f16)v.y; h[2] = (f16)v.z; h[3] = (f16)v.w;
    *(half4*)(dst + i) = h;
  }
}

// ---------------------------------------------------------------- RoPE (in-place, f16, strided)
__global__ __launch_bounds__(256) void rope_inplace(f16* __restrict__ X,
                                                    const int* __restrict__ pos,
                                                    int rows, int width, int ld,
                                                    int S, float scale) {
  const int cp = width >> 1;
  const int total = rows * cp;
  const float kf = -0.41524101186092027f;  // -log2(10000)/32
  const int step = gridDim.x * blockDim.x;
  for (int p = blockIdx.x * blockDim.x + threadIdx.x; p < total; p += step) {
    const int row = p / cp;
    const int pi = p - row * cp;
    const int i = pi & 31;  // pair index within 64-wide head
    const float ang = (float)pos[row % S] * exp2f(kf * (float)i);
    float s, c;
    sincosf(ang, &s, &c);
    f16* ptr = X + (size_t)row * ld + (pi << 1);
    const float x1 = (float)ptr[0], x2 = (float)ptr[1];
    ptr[0] = (f16)((x1 * c - x2 * s) * scale);
    ptr[1] = (f16)((x1 * s + x2 * c) * scale);
  }
}

// ---------------------------------------------------------------- GEMM: C = A @ B^T
// A[M][K], B[N][K] f16 row-major; C f32 (OUT_F32=1) or f16 (OUT_F32=0).
template <int OUT_F32>
__global__ __launch_bounds__(256) void gemm_bt(const f16* __restrict__ A,
                                               const f16* __restrict__ B,
                                               void* __restrict__ Cv,
                                               int M, int N, int K) {
  __shared__ alignas(16) f16 As[128][32];
  __shared__ alignas(16) f16 Bs[128][32];
  const int tid = threadIdx.x;
  const int w = tid >> 6, l = tid & 63;
  const int m0 = blockIdx.y << 7, n0 = blockIdx.x << 7;
  const int wr = (w >> 1) << 6, wc = (w & 1) << 6;
  const int fr = l & 15;
  const int fk = (l >> 4) << 3;
  const int srow = l >> 2;
  const int scol = (l & 3) << 3;

  f32x4 acc[4][4] = {};

  for (int k0 = 0; k0 < K; k0 += 32) {
#pragma unroll
    for (int c = 0; c < 2; ++c) {
      const int rb = (w * 2 + c) * 16;
      gload_lds16(A + (size_t)(m0 + rb + srow) * K + k0 + scol, &As[rb][0]);
      gload_lds16(B + (size_t)(n0 + rb + srow) * K + k0 + scol, &Bs[rb][0]);
    }
    __syncthreads();
    half8 af[4], bfr[4];
#pragma unroll
    for (int i = 0; i < 4; ++i) af[i] = *(const half8*)&As[wr + i * 16 + fr][fk];
#pragma unroll
    for (int j = 0; j < 4; ++j) bfr[j] = *(const half8*)&Bs[wc + j * 16 + fr][fk];
#pragma unroll
    for (int i = 0; i < 4; ++i)
#pragma unroll
      for (int j = 0; j < 4; ++j)
        acc[i][j] = __builtin_amdgcn_mfma_f32_16x16x32_f16(af[i], bfr[j], acc[i][j], 0, 0, 0);
    __syncthreads();
  }

  const int orow = (l >> 4) << 2;
#pragma unroll
  for (int i = 0; i < 4; ++i) {
#pragma unroll
    for (int j = 0; j < 4; ++j) {
      const int col = n0 + wc + j * 16 + fr;
#pragma unroll
      for (int r = 0; r < 4; ++r) {
        const size_t idx = (size_t)(m0 + wr + i * 16 + orow + r) * N + col;
        if (OUT_F32) ((float*)Cv)[idx] = acc[i][j][r];
        else ((f16*)Cv)[idx] = (f16)acc[i][j][r];
      }
    }
  }
}

// ---------------------------------------------------------------- causal GQA attention v2
// QKV: [B*S][3072] f16 (Q cols 0..2047 roped+scaled, K 2048..2559 roped, V 2560..3071)
// O:   [B*S][2048] f16.
// Paired q-tiles (qt, 15-qt): every block does exactly 17 tile-computations.
// Ks/Vt XOR-swizzled (16B slot ^= row&7) -> conflict-free ds_read_b128/write_b128.
__global__ __launch_bounds__(256) void attn_fwd(const f16* __restrict__ QKV,
                                                f16* __restrict__ O) {
  // bijective XCD swizzle over 512 blocks: blocks sharing a KV head land together
  const int flat = blockIdx.x + (blockIdx.y << 3) + (blockIdx.z << 8);
  const int rmid = ((flat & 7) << 6) + (flat >> 3);
  const int pr = rmid & 7, h = (rmid >> 3) & 31, b = rmid >> 8;
  const int kvh = h >> 2;
  const int tid = threadIdx.x, w = tid >> 6, l = tid & 63;
  const int fr = l & 15, g = l >> 4;
  const int orow = g << 2;
  const int qtA = pr, qtB = 15 - pr;

  __shared__ alignas(16) char KsB[8192];
  __shared__ alignas(16) char VtB[8192];
  __shared__ alignas(16) f16 Ps[4][16][72];

  auto KS = [&](int row, int slot) -> f16* {
    return (f16*)(KsB + row * 128 + ((slot ^ (row & 7)) << 4));
  };
  auto VT = [&](int d, int oct) -> f16* {
    return (f16*)(VtB + d * 128 + ((oct ^ (d & 7)) << 4));
  };

  // Q fragments (two q-tiles) in registers
  const size_t qoff = (size_t)(b * 1024 + w * 16 + fr) * 3072 + h * 64 + (g << 3);
  const f16* qA = QKV + qoff + (size_t)qtA * 64 * 3072;
  const f16* qB = QKV + qoff + (size_t)qtB * 64 * 3072;
  const half8 aA0 = *(const half8*)qA, aA1 = *(const half8*)(qA + 32);
  const half8 aB0 = *(const half8*)qB, aB1 = *(const half8*)(qB + 32);

  float rmA[4], rlA[4], rmB[4], rlB[4];
  f32x4 oA[4] = {}, oB[4] = {};
#pragma unroll
  for (int r = 0; r < 4; ++r) { rmA[r] = rmB[r] = -3.0e38f; rlA[r] = rlB[r] = 0.f; }

  const int srow = tid >> 3, sds = tid & 7;    // K staging: 8 lanes/row
  const int vd = tid & 63, voct0 = tid >> 6;   // V staging: transposed

  const f16* Kbase = QKV + 2048 + kvh * 64;
  const f16* Vbase = QKV + 2560 + kvh * 64;

  auto compute = [&](const half8& a0, const half8& a1, float* rm, float* rl,
                     f32x4* o, int qt, int kt) {
    f32x4 s4[4] = {};
#pragma unroll
    for (int j = 0; j < 4; ++j) {
      const half8 bk0 = *(const half8*)KS(j * 16 + fr, g);
      const half8 bk1 = *(const half8*)KS(j * 16 + fr, 4 + g);
      s4[j] = __builtin_amdgcn_mfma_f32_16x16x32_f16(a0, bk0, s4[j], 0, 0, 0);
      s4[j] = __builtin_amdgcn_mfma_f32_16x16x32_f16(a1, bk1, s4[j], 0, 0, 0);
    }
    if (kt == qt) {  // diagonal tile: causal mask
      const int qrow0 = qt * 64 + w * 16 + orow;
#pragma unroll
      for (int j = 0; j < 4; ++j) {
        const int col = kt * 64 + j * 16 + fr;
#pragma unroll
        for (int r = 0; r < 4; ++r)
          if (col > qrow0 + r) s4[j][r] = -1.0e30f;
      }
    }
#pragma unroll
    for (int r = 0; r < 4; ++r) {
      float mx = fmaxf(fmaxf(s4[0][r], s4[1][r]), fmaxf(s4[2][r], s4[3][r]));
#pragma unroll
      for (int off = 8; off >= 1; off >>= 1) mx = fmaxf(mx, __shfl_xor(mx, off));
      const float mn = fmaxf(rm[r], mx);
      const float sf = __expf(rm[r] - mn);
      rl[r] *= sf;
      o[0][r] *= sf; o[1][r] *= sf; o[2][r] *= sf; o[3][r] *= sf;
      rm[r] = mn;
    }
    float ps[4] = {0.f, 0.f, 0.f, 0.f};
#pragma unroll
    for (int j = 0; j < 4; ++j)
#pragma unroll
      for (int r = 0; r < 4; ++r) {
        const float p = __expf(s4[j][r] - rm[r]);
        ps[r] += p;
        Ps[w][orow + r][j * 16 + fr] = (f16)p;
      }
#pragma unroll
    for (int r = 0; r < 4; ++r) {
      float t = ps[r];
#pragma unroll
      for (int off = 8; off >= 1; off >>= 1) t += __shfl_xor(t, off);
      rl[r] += t;
    }
#pragma unroll
    for (int kv2 = 0; kv2 < 2; ++kv2) {
      const half8 ap = *(const half8*)&Ps[w][fr][kv2 * 32 + (g << 3)];
#pragma unroll
      for (int j = 0; j < 4; ++j) {
        const half8 bv = *(const half8*)VT(j * 16 + fr, kv2 * 4 + g);
        o[j] = __builtin_amdgcn_mfma_f32_16x16x32_f16(ap, bv, o[j], 0, 0, 0);
      }
    }
  };

  for (int kt = 0; kt <= qtB; ++kt) {
    const int kvr = b * 1024 + (kt << 6);
    // ---- stage K (row-major, swizzled)
#pragma unroll
    for (int p = 0; p < 2; ++p) {
      const int row = srow + (p << 5);
      *(half8*)KS(row, sds) = *(const half8*)(Kbase + (size_t)(kvr + row) * 3072 + sds * 8);
    }
    // ---- stage V^T: coalesced transposed global reads + vectorized swizzled writes
#pragma unroll
    for (int it = 0; it < 2; ++it) {
      const int oct = voct0 + (it << 2);
      const f16* gv = Vbase + (size_t)(kvr + oct * 8) * 3072 + vd;
      half8 vv;
#pragma unroll
      for (int m = 0; m < 8; ++m) vv[m] = gv[(size_t)m * 3072];
      *(half8*)VT(vd, oct) = vv;
    }
    __syncthreads();
    if (kt <= qtA) compute(aA0, aA1, rmA, rlA, oA, qtA, kt);
    compute(aB0, aB1, rmB, rlB, oB, qtB, kt);
    __syncthreads();
  }

#pragma unroll
  for (int j = 0; j < 4; ++j)
#pragma unroll
    for (int r = 0; r < 4; ++r) {
      const int rowA = qtA * 64 + w * 16 + orow + r;
      const int rowB = qtB * 64 + w * 16 + orow + r;
      const int col = h * 64 + j * 16 + fr;
      O[(size_t)(b * 1024 + rowA) * 2048 + col] = (f16)(oA[j][r] / rlA[r]);
      O[(size_t)(b * 1024 + rowB) * 2048 + col] = (f16)(oB[j][r] / rlB[r]);
    }
}

// ---------------------------------------------------------------- launch
extern "C" void kernel_launch(void* const* d_in, const int* in_sizes, int n_in,
                              void* d_out, int out_size, void* d_ws, size_t ws_size,
                              hipStream_t stream) {
  const float* X = (const float*)d_in[0];
  const int* tokpos = (const int*)d_in[1];
  const float* qw = (const float*)d_in[2];
  const float* kw = (const float*)d_in[3];
  const float* vw = (const float*)d_in[4];
  const float* ow = (const float*)d_in[5];

  constexpr int B = 2, S = 1024, D = 2048, DKV = 512, H = 32;
  constexpr int M = B * S;        // 2048
  constexpr int NQKV = D + 2 * DKV;  // 3072

  char* ws = (char*)d_ws;
  f16* Xh   = (f16*)(ws);                    //  8 MiB: X f16
  f16* QKVW = (f16*)(ws + (8u << 20));       // 12 MiB: concat [q_w; k_w; v_w] rows
  f16* owh  = (f16*)(ws + (20u << 20));      //  8 MiB
  f16* QKVc = (f16*)(ws + (28u << 20));      // 12 MiB: [2048][3072] fused Q|K|V
  f16* Ah   = (f16*)(ws + (40u << 20));      //  8 MiB: attention output

  // fp32 -> f16 (weights concatenated into one B matrix for the fused GEMM)
  cvt_f32_f16<<<2048, 256, 0, stream>>>(X, Xh, M * D);
  cvt_f32_f16<<<2048, 256, 0, stream>>>(qw, QKVW, D * D);
  cvt_f32_f16<<<1024, 256, 0, stream>>>(kw, QKVW + (size_t)D * D, DKV * D);
  cvt_f32_f16<<<1024, 256, 0, stream>>>(vw, QKVW + (size_t)(D + DKV) * D, DKV * D);
  cvt_f32_f16<<<2048, 256, 0, stream>>>(ow, owh, D * D);

  // fused QKV projection: [2048][3072] = X @ [q_w;k_w;v_w]^T
  gemm_bt<0><<<dim3(NQKV / 128, M / 128), 256, 0, stream>>>(Xh, QKVW, QKVc, M, NQKV, D);

  // RoPE in place (Q absorbs the 1/sqrt(64)=0.125 score scale)
  rope_inplace<<<2048, 256, 0, stream>>>(QKVc, tokpos, M, D, NQKV, S, 0.125f);
  rope_inplace<<<512, 256, 0, stream>>>(QKVc + D, tokpos, M, DKV, NQKV, S, 1.0f);

  // causal GQA attention (paired q-tiles, 512 blocks)
  attn_fwd<<<dim3(8, H, B), 256, 0, stream>>>(QKVc, Ah);

  // output projection -> fp32 d_out
  gemm_bt<1><<<dim3(D / 128, M / 128), 256, 0, stream>>>(Ah, owh, d_out, M, D, D);
}

// Round 3
// 151.051 us; speedup vs baseline: 2.0880x; 1.1424x over previous
//
#include <hip/hip_runtime.h>

typedef _Float16 f16;
typedef _Float16 half8 __attribute__((ext_vector_type(8), may_alias));
typedef _Float16 half4 __attribute__((ext_vector_type(4), may_alias));
typedef float f32x4 __attribute__((ext_vector_type(4), may_alias));

#define ROPE_KF -0.41524101186092027f  // -log2(10000)/32

// ---------------------------------------------------------------- helpers
__device__ __forceinline__ void gload_lds16(const f16* g, f16* lds) {
  __builtin_amdgcn_global_load_lds(
      (const __attribute__((address_space(1))) void*)g,
      (__attribute__((address_space(3))) void*)lds, 16, 0, 0);
}

// rotate 4 interleaved pairs of a half8; i0 = pair index of v[0..1] within head
__device__ __forceinline__ half8 rope8(half8 v, float posf, int i0, float scale) {
  half8 r;
#pragma unroll
  for (int p = 0; p < 4; ++p) {
    const float ang = posf * exp2f(ROPE_KF * (float)(i0 + p));
    float s, c;
    sincosf(ang, &s, &c);
    const float x1 = (float)v[2 * p], x2 = (float)v[2 * p + 1];
    r[2 * p]     = (f16)((x1 * c - x2 * s) * scale);
    r[2 * p + 1] = (f16)((x1 * s + x2 * c) * scale);
  }
  return r;
}

// ---------------------------------------------------------------- fused fp32 -> f16 (5 segments)
__global__ __launch_bounds__(256) void cvt_all(const float* __restrict__ s0, f16* __restrict__ d0, int n0,
                                               const float* __restrict__ s1, f16* __restrict__ d1, int n1,
                                               const float* __restrict__ s2, f16* __restrict__ d2, int n2,
                                               const float* __restrict__ s3, f16* __restrict__ d3, int n3,
                                               const float* __restrict__ s4, f16* __restrict__ d4, int n4) {
  const int step = gridDim.x * blockDim.x * 4;
  const int base = (blockIdx.x * blockDim.x + threadIdx.x) * 4;
  auto go = [&](const float* s, f16* d, int n) {
    for (int i = base; i < n; i += step) {
      float4 v = *(const float4*)(s + i);
      half4 h;
      h[0] = (f16)v.x; h[1] = (f16)v.y; h[2] = (f16)v.z; h[3] = (f16)v.w;
      *(half4*)(d + i) = h;
    }
  };
  go(s0, d0, n0); go(s1, d1, n1); go(s2, d2, n2); go(s3, d3, n3); go(s4, d4, n4);
}

// ---------------------------------------------------------------- GEMM: C = A @ B^T
// A[M][K], B[N][K] f16 row-major; C f32 (OUT_F32=1) or f16 (OUT_F32=0).
// 64x128 tile, BK=32, 4 waves (wave owns 64M x 32N), double-buffered LDS with
// next-tile global_load_lds issued before current-tile compute (1 barrier/K-step).
// LDS 16B-slot swizzle: slot ^= (row>>1)&3, applied via pre-swizzled global src.
template <int OUT_F32>
__global__ __launch_bounds__(256) void gemm_bt(const f16* __restrict__ A,
                                               const f16* __restrict__ B,
                                               void* __restrict__ Cv,
                                               int M, int N, int K) {
  __shared__ alignas(16) f16 As[2][64][32];
  __shared__ alignas(16) f16 Bs[2][128][32];
  const int tid = threadIdx.x;
  const int w = tid >> 6, l = tid & 63;
  const int m0 = blockIdx.y << 6, n0 = blockIdx.x << 7;
  const int fr = l & 15;
  // swizzled fragment col offset: slot (l>>4) xor lane-constant row term ((fr>>1)&3)
  const int fkz = (((l >> 4) ^ ((fr >> 1) & 3)) << 3);
  // staging: lane l covers row (chunkbase + l/4), 16B slot l&3; global col block
  // pre-swizzled so linear LDS writes land in swizzled layout
  const int srow = l >> 2;
  const int scol = (((l & 3) ^ ((l >> 3) & 3)) << 3);

  const f16* ga  = A + (size_t)(m0 + w * 16 + srow) * K + scol;
  const f16* gb0 = B + (size_t)(n0 + w * 16 + srow) * K + scol;
  const f16* gb1 = B + (size_t)(n0 + 64 + w * 16 + srow) * K + scol;

  auto stage = [&](int buf, int k0) {
    gload_lds16(ga + k0, &As[buf][w * 16][0]);
    gload_lds16(gb0 + k0, &Bs[buf][w * 16][0]);
    gload_lds16(gb1 + k0, &Bs[buf][64 + w * 16][0]);
  };

  f32x4 acc[4][2] = {};

  stage(0, 0);
  __syncthreads();
  const int nk = K >> 5;
  for (int t = 0; t < nk; ++t) {
    const int buf = t & 1;
    if (t + 1 < nk) stage(buf ^ 1, (t + 1) << 5);  // prefetch next K-tile
    half8 af[4], bf[2];
#pragma unroll
    for (int i = 0; i < 4; ++i) af[i] = *(const half8*)&As[buf][i * 16 + fr][fkz];
#pragma unroll
    for (int j = 0; j < 2; ++j) bf[j] = *(const half8*)&Bs[buf][w * 32 + j * 16 + fr][fkz];
#pragma unroll
    for (int i = 0; i < 4; ++i)
#pragma unroll
      for (int j = 0; j < 2; ++j)
        acc[i][j] = __builtin_amdgcn_mfma_f32_16x16x32_f16(af[i], bf[j], acc[i][j], 0, 0, 0);
    __syncthreads();  // drains prefetch vmcnt + guards buffer reuse
  }

  const int orow = (l >> 4) << 2;
#pragma unroll
  for (int i = 0; i < 4; ++i) {
#pragma unroll
    for (int j = 0; j < 2; ++j) {
      const int col = n0 + w * 32 + j * 16 + fr;
#pragma unroll
      for (int r = 0; r < 4; ++r) {
        const size_t idx = (size_t)(m0 + i * 16 + orow + r) * N + col;
        if (OUT_F32) ((float*)Cv)[idx] = acc[i][j][r];
        else ((f16*)Cv)[idx] = (f16)acc[i][j][r];
      }
    }
  }
}

// ---------------------------------------------------------------- causal GQA attention v3
// QKV: [B*S][3072] f16 UN-roped (Q cols 0..2047, K 2048..2559, V 2560..3071).
// RoPE applied in-kernel: Q at register load (+0.125 scale), K at LDS stage.
// O: [B*S][2048] f16.  Paired q-tiles (qt, 15-qt): uniform 17 tile-computations.
__global__ __launch_bounds__(256) void attn_fwd(const f16* __restrict__ QKV,
                                                const int* __restrict__ pos,
                                                f16* __restrict__ O) {
  // bijective XCD swizzle over 512 blocks: blocks sharing a KV head land together
  const int flat = blockIdx.x + (blockIdx.y << 3) + (blockIdx.z << 8);
  const int rmid = ((flat & 7) << 6) + (flat >> 3);
  const int pr = rmid & 7, h = (rmid >> 3) & 31, b = rmid >> 8;
  const int kvh = h >> 2;
  const int tid = threadIdx.x, w = tid >> 6, l = tid & 63;
  const int fr = l & 15, g = l >> 4;
  const int orow = g << 2;
  const int qtA = pr, qtB = 15 - pr;

  __shared__ alignas(16) char KsB[8192];
  __shared__ alignas(16) char VtB[8192];
  __shared__ alignas(16) f16 Ps[4][16][72];

  auto KS = [&](int row, int slot) -> f16* {
    return (f16*)(KsB + row * 128 + ((slot ^ (row & 7)) << 4));
  };
  auto VT = [&](int d, int oct) -> f16* {
    return (f16*)(VtB + d * 128 + ((oct ^ (d & 7)) << 4));
  };

  // Q fragments (two q-tiles) in registers, roped + scaled
  const int sA = qtA * 64 + w * 16 + fr, sB = qtB * 64 + w * 16 + fr;
  const float pA = (float)pos[sA], pB = (float)pos[sB];
  const size_t qoff = (size_t)(b * 1024 + w * 16 + fr) * 3072 + h * 64 + (g << 3);
  const f16* qA = QKV + qoff + (size_t)qtA * 64 * 3072;
  const f16* qB = QKV + qoff + (size_t)qtB * 64 * 3072;
  const half8 aA0 = rope8(*(const half8*)qA, pA, g << 2, 0.125f);
  const half8 aA1 = rope8(*(const half8*)(qA + 32), pA, 16 + (g << 2), 0.125f);
  const half8 aB0 = rope8(*(const half8*)qB, pB, g << 2, 0.125f);
  const half8 aB1 = rope8(*(const half8*)(qB + 32), pB, 16 + (g << 2), 0.125f);

  float rmA[4], rlA[4], rmB[4], rlB[4];
  f32x4 oA[4] = {}, oB[4] = {};
#pragma unroll
  for (int r = 0; r < 4; ++r) { rmA[r] = rmB[r] = -3.0e38f; rlA[r] = rlB[r] = 0.f; }

  const int srow = tid >> 3, sds = tid & 7;    // K staging: 8 lanes/row
  const int vd = tid & 63, voct0 = tid >> 6;   // V staging: transposed

  const f16* Kbase = QKV + 2048 + kvh * 64;
  const f16* Vbase = QKV + 2560 + kvh * 64;

  auto compute = [&](const half8& a0, const half8& a1, float* rm, float* rl,
                     f32x4* o, int qt, int kt) {
    f32x4 s4[4] = {};
#pragma unroll
    for (int j = 0; j < 4; ++j) {
      const half8 bk0 = *(const half8*)KS(j * 16 + fr, g);
      const half8 bk1 = *(const half8*)KS(j * 16 + fr, 4 + g);
      s4[j] = __builtin_amdgcn_mfma_f32_16x16x32_f16(a0, bk0, s4[j], 0, 0, 0);
      s4[j] = __builtin_amdgcn_mfma_f32_16x16x32_f16(a1, bk1, s4[j], 0, 0, 0);
    }
    if (kt == qt) {  // diagonal tile: causal mask
      const int qrow0 = qt * 64 + w * 16 + orow;
#pragma unroll
      for (int j = 0; j < 4; ++j) {
        const int col = kt * 64 + j * 16 + fr;
#pragma unroll
        for (int r = 0; r < 4; ++r)
          if (col > qrow0 + r) s4[j][r] = -1.0e30f;
      }
    }
#pragma unroll
    for (int r = 0; r < 4; ++r) {
      float mx = fmaxf(fmaxf(s4[0][r], s4[1][r]), fmaxf(s4[2][r], s4[3][r]));
#pragma unroll
      for (int off = 8; off >= 1; off >>= 1) mx = fmaxf(mx, __shfl_xor(mx, off));
      const float mn = fmaxf(rm[r], mx);
      const float sf = __expf(rm[r] - mn);
      rl[r] *= sf;
      o[0][r] *= sf; o[1][r] *= sf; o[2][r] *= sf; o[3][r] *= sf;
      rm[r] = mn;
    }
    float ps[4] = {0.f, 0.f, 0.f, 0.f};
#pragma unroll
    for (int j = 0; j < 4; ++j)
#pragma unroll
      for (int r = 0; r < 4; ++r) {
        const float p = __expf(s4[j][r] - rm[r]);
        ps[r] += p;
        Ps[w][orow + r][j * 16 + fr] = (f16)p;
      }
#pragma unroll
    for (int r = 0; r < 4; ++r) {
      float t = ps[r];
#pragma unroll
      for (int off = 8; off >= 1; off >>= 1) t += __shfl_xor(t, off);
      rl[r] += t;
    }
#pragma unroll
    for (int kv2 = 0; kv2 < 2; ++kv2) {
      const half8 ap = *(const half8*)&Ps[w][fr][kv2 * 32 + (g << 3)];
#pragma unroll
      for (int j = 0; j < 4; ++j) {
        const half8 bv = *(const half8*)VT(j * 16 + fr, kv2 * 4 + g);
        o[j] = __builtin_amdgcn_mfma_f32_16x16x32_f16(ap, bv, o[j], 0, 0, 0);
      }
    }
  };

  for (int kt = 0; kt <= qtB; ++kt) {
    const int kvr = b * 1024 + (kt << 6);
    // ---- stage K (row-major, swizzled, roped)
#pragma unroll
    for (int p = 0; p < 2; ++p) {
      const int row = srow + (p << 5);
      half8 kk = *(const half8*)(Kbase + (size_t)(kvr + row) * 3072 + sds * 8);
      kk = rope8(kk, (float)pos[(kt << 6) + row], sds << 2, 1.0f);
      *(half8*)KS(row, sds) = kk;
    }
    // ---- stage V^T: coalesced transposed global reads + vectorized swizzled writes
#pragma unroll
    for (int it = 0; it < 2; ++it) {
      const int oct = voct0 + (it << 2);
      const f16* gv = Vbase + (size_t)(kvr + oct * 8) * 3072 + vd;
      half8 vv;
#pragma unroll
      for (int m = 0; m < 8; ++m) vv[m] = gv[(size_t)m * 3072];
      *(half8*)VT(vd, oct) = vv;
    }
    __syncthreads();
    if (kt <= qtA) compute(aA0, aA1, rmA, rlA, oA, qtA, kt);
    compute(aB0, aB1, rmB, rlB, oB, qtB, kt);
    __syncthreads();
  }

#pragma unroll
  for (int j = 0; j < 4; ++j)
#pragma unroll
    for (int r = 0; r < 4; ++r) {
      const int rowA = qtA * 64 + w * 16 + orow + r;
      const int rowB = qtB * 64 + w * 16 + orow + r;
      const int col = h * 64 + j * 16 + fr;
      O[(size_t)(b * 1024 + rowA) * 2048 + col] = (f16)(oA[j][r] / rlA[r]);
      O[(size_t)(b * 1024 + rowB) * 2048 + col] = (f16)(oB[j][r] / rlB[r]);
    }
}

// ---------------------------------------------------------------- launch
extern "C" void kernel_launch(void* const* d_in, const int* in_sizes, int n_in,
                              void* d_out, int out_size, void* d_ws, size_t ws_size,
                              hipStream_t stream) {
  const float* X = (const float*)d_in[0];
  const int* tokpos = (const int*)d_in[1];
  const float* qw = (const float*)d_in[2];
  const float* kw = (const float*)d_in[3];
  const float* vw = (const float*)d_in[4];
  const float* ow = (const float*)d_in[5];

  constexpr int B = 2, S = 1024, D = 2048, DKV = 512, H = 32;
  constexpr int M = B * S;           // 2048
  constexpr int NQKV = D + 2 * DKV;  // 3072

  char* ws = (char*)d_ws;
  f16* Xh   = (f16*)(ws);                    //  8 MiB: X f16
  f16* QKVW = (f16*)(ws + (8u << 20));       // 12 MiB: concat [q_w; k_w; v_w] rows
  f16* owh  = (f16*)(ws + (20u << 20));      //  8 MiB
  f16* QKVc = (f16*)(ws + (28u << 20));      // 12 MiB: [2048][3072] fused Q|K|V (un-roped)
  f16* Ah   = (f16*)(ws + (40u << 20));      //  8 MiB: attention output

  // fp32 -> f16, all five arrays in one dispatch
  cvt_all<<<2048, 256, 0, stream>>>(X, Xh, M * D,
                                    qw, QKVW, D * D,
                                    kw, QKVW + (size_t)D * D, DKV * D,
                                    vw, QKVW + (size_t)(D + DKV) * D, DKV * D,
                                    ow, owh, D * D);

  // fused QKV projection: [2048][3072] = X @ [q_w;k_w;v_w]^T
  gemm_bt<0><<<dim3(NQKV / 128, M / 64), 256, 0, stream>>>(Xh, QKVW, QKVc, M, NQKV, D);

  // causal GQA attention (RoPE fused; paired q-tiles, 512 blocks)
  attn_fwd<<<dim3(8, H, B), 256, 0, stream>>>(QKVc, tokpos, Ah);

  // output projection -> fp32 d_out
  gemm_bt<1><<<dim3(D / 128, M / 64), 256, 0, stream>>>(Ah, owh, d_out, M, D, D);
}

// Round 4
// 140.168 us; speedup vs baseline: 2.2502x; 1.0776x over previous
//
#include <hip/hip_runtime.h>

typedef _Float16 f16;
typedef _Float16 half8 __attribute__((ext_vector_type(8), may_alias));
typedef _Float16 half4 __attribute__((ext_vector_type(4), may_alias));
typedef float f32x4 __attribute__((ext_vector_type(4), may_alias));

#define ROPE_KF -0.41524101186092027f  // -log2(10000)/32

// ---------------------------------------------------------------- helpers
__device__ __forceinline__ void gload_lds16(const f16* g, f16* lds) {
  __builtin_amdgcn_global_load_lds(
      (const __attribute__((address_space(1))) void*)g,
      (__attribute__((address_space(3))) void*)lds, 16, 0, 0);
}

// rotate 4 interleaved pairs of a half8; i0 = pair index of v[0..1] within head
__device__ __forceinline__ half8 rope8(half8 v, float posf, int i0, float scale) {
  half8 r;
#pragma unroll
  for (int p = 0; p < 4; ++p) {
    const float ang = posf * exp2f(ROPE_KF * (float)(i0 + p));
    float s, c;
    sincosf(ang, &s, &c);
    const float x1 = (float)v[2 * p], x2 = (float)v[2 * p + 1];
    r[2 * p]     = (f16)((x1 * c - x2 * s) * scale);
    r[2 * p + 1] = (f16)((x1 * s + x2 * c) * scale);
  }
  return r;
}

// ---------------------------------------------------------------- fused fp32 -> f16 (5 segments)
__global__ __launch_bounds__(256) void cvt_all(const float* __restrict__ s0, f16* __restrict__ d0, int n0,
                                               const float* __restrict__ s1, f16* __restrict__ d1, int n1,
                                               const float* __restrict__ s2, f16* __restrict__ d2, int n2,
                                               const float* __restrict__ s3, f16* __restrict__ d3, int n3,
                                               const float* __restrict__ s4, f16* __restrict__ d4, int n4) {
  const int step = gridDim.x * blockDim.x * 4;
  const int base = (blockIdx.x * blockDim.x + threadIdx.x) * 4;
  auto go = [&](const float* s, f16* d, int n) {
    for (int i = base; i < n; i += step) {
      float4 v = *(const float4*)(s + i);
      half4 h;
      h[0] = (f16)v.x; h[1] = (f16)v.y; h[2] = (f16)v.z; h[3] = (f16)v.w;
      *(half4*)(d + i) = h;
    }
  };
  go(s0, d0, n0); go(s1, d1, n1); go(s2, d2, n2); go(s3, d3, n3); go(s4, d4, n4);
}

// ---------------------------------------------------------------- GEMM: C = A @ B^T
// 64x128 tile, BK=32, 4 waves, double-buffered LDS, pre-swizzled staging.
template <int OUT_F32>
__global__ __launch_bounds__(256) void gemm_bt(const f16* __restrict__ A,
                                               const f16* __restrict__ B,
                                               void* __restrict__ Cv,
                                               int M, int N, int K) {
  __shared__ alignas(16) f16 As[2][64][32];
  __shared__ alignas(16) f16 Bs[2][128][32];
  const int tid = threadIdx.x;
  const int w = tid >> 6, l = tid & 63;
  const int m0 = blockIdx.y << 6, n0 = blockIdx.x << 7;
  const int fr = l & 15;
  const int fkz = (((l >> 4) ^ ((fr >> 1) & 3)) << 3);
  const int srow = l >> 2;
  const int scol = (((l & 3) ^ ((l >> 3) & 3)) << 3);

  const f16* ga  = A + (size_t)(m0 + w * 16 + srow) * K + scol;
  const f16* gb0 = B + (size_t)(n0 + w * 16 + srow) * K + scol;
  const f16* gb1 = B + (size_t)(n0 + 64 + w * 16 + srow) * K + scol;

  auto stage = [&](int buf, int k0) {
    gload_lds16(ga + k0, &As[buf][w * 16][0]);
    gload_lds16(gb0 + k0, &Bs[buf][w * 16][0]);
    gload_lds16(gb1 + k0, &Bs[buf][64 + w * 16][0]);
  };

  f32x4 acc[4][2] = {};

  stage(0, 0);
  __syncthreads();
  const int nk = K >> 5;
  for (int t = 0; t < nk; ++t) {
    const int buf = t & 1;
    if (t + 1 < nk) stage(buf ^ 1, (t + 1) << 5);
    half8 af[4], bf[2];
#pragma unroll
    for (int i = 0; i < 4; ++i) af[i] = *(const half8*)&As[buf][i * 16 + fr][fkz];
#pragma unroll
    for (int j = 0; j < 2; ++j) bf[j] = *(const half8*)&Bs[buf][w * 32 + j * 16 + fr][fkz];
#pragma unroll
    for (int i = 0; i < 4; ++i)
#pragma unroll
      for (int j = 0; j < 2; ++j)
        acc[i][j] = __builtin_amdgcn_mfma_f32_16x16x32_f16(af[i], bf[j], acc[i][j], 0, 0, 0);
    __syncthreads();
  }

  const int orow = (l >> 4) << 2;
#pragma unroll
  for (int i = 0; i < 4; ++i) {
#pragma unroll
    for (int j = 0; j < 2; ++j) {
      const int col = n0 + w * 32 + j * 16 + fr;
#pragma unroll
      for (int r = 0; r < 4; ++r) {
        const size_t idx = (size_t)(m0 + i * 16 + orow + r) * N + col;
        if (OUT_F32) ((float*)Cv)[idx] = acc[i][j][r];
        else ((f16*)Cv)[idx] = (f16)acc[i][j][r];
      }
    }
  }
}

// ---------------------------------------------------------------- K/V repack
// One-time: rope K, transpose V, write both per-(b,kvh,kt) as 8KB tiles in the
// EXACT pre-swizzled byte order attention's LDS consumes (linear DMA copy there).
// Kp tile: f16 offset = row*64 + ((slot ^ (row&7))<<3)      row=kv, slot=d/8
// Vt tile: f16 offset = d*64   + ((oct  ^ (d&7))<<3)        oct = s_in_tile/8
__global__ __launch_bounds__(256) void repack_kv(const f16* __restrict__ QKV,
                                                 const int* __restrict__ pos,
                                                 f16* __restrict__ Kp,
                                                 f16* __restrict__ Vt) {
  const int kt = blockIdx.x, kvh = blockIdx.y, b = blockIdx.z;
  const int tid = threadIdx.x;
  __shared__ f16 vs[64][72];
  const size_t tile = ((size_t)((b * 8 + kvh) * 16 + kt)) * 4096;
  const f16* kbase = QKV + 2048 + kvh * 64;
  const f16* vbase = QKV + 2560 + kvh * 64;
#pragma unroll
  for (int p = 0; p < 2; ++p) {
    const int c = tid + p * 256;
    const int row = c >> 3, slot = c & 7;
    const size_t grow = (size_t)(b * 1024 + kt * 64 + row) * 3072;
    half8 kk = *(const half8*)(kbase + grow + slot * 8);
    kk = rope8(kk, (float)pos[kt * 64 + row], slot << 2, 1.0f);
    *(half8*)(Kp + tile + row * 64 + ((slot ^ (row & 7)) << 3)) = kk;
    *(half8*)&vs[row][slot * 8] = *(const half8*)(vbase + grow + slot * 8);
  }
  __syncthreads();
#pragma unroll
  for (int p = 0; p < 2; ++p) {
    const int c = tid + p * 256;
    const int d = c >> 3, oct = c & 7;
    half8 vv;
#pragma unroll
    for (int m = 0; m < 8; ++m) vv[m] = vs[oct * 8 + m][d];
    *(half8*)(Vt + tile + d * 64 + ((oct ^ (d & 7)) << 3)) = vv;
  }
}

// ---------------------------------------------------------------- causal GQA attention v4
// Q from QKV (roped in-register once, +0.125 scale); K/V from pre-swizzled
// tiles via pure-DMA double-buffered staging. Paired q-tiles (qt, 15-qt).
__global__ __launch_bounds__(256) void attn_fwd(const f16* __restrict__ QKV,
                                                const f16* __restrict__ Kp,
                                                const f16* __restrict__ Vt,
                                                const int* __restrict__ pos,
                                                f16* __restrict__ O) {
  const int flat = blockIdx.x + (blockIdx.y << 3) + (blockIdx.z << 8);
  const int rmid = ((flat & 7) << 6) + (flat >> 3);
  const int pr = rmid & 7, h = (rmid >> 3) & 31, b = rmid >> 8;
  const int kvh = h >> 2;
  const int tid = threadIdx.x, w = tid >> 6, l = tid & 63;
  const int fr = l & 15, g = l >> 4;
  const int orow = g << 2;
  const int qtA = pr, qtB = 15 - pr;

  __shared__ alignas(16) char KsB[2][8192];
  __shared__ alignas(16) char VtB[2][8192];
  __shared__ alignas(16) f16 Ps[4][16][72];

  auto KS = [&](int buf, int row, int slot) -> f16* {
    return (f16*)(KsB[buf] + row * 128 + ((slot ^ (row & 7)) << 4));
  };
  auto VT = [&](int buf, int d, int oct) -> f16* {
    return (f16*)(VtB[buf] + d * 128 + ((oct ^ (d & 7)) << 4));
  };

  // Q fragments (two q-tiles) in registers, roped + scaled
  const int sA = qtA * 64 + w * 16 + fr, sB = qtB * 64 + w * 16 + fr;
  const float pA = (float)pos[sA], pB = (float)pos[sB];
  const size_t qoff = (size_t)(b * 1024 + w * 16 + fr) * 3072 + h * 64 + (g << 3);
  const f16* qA = QKV + qoff + (size_t)qtA * 64 * 3072;
  const f16* qB = QKV + qoff + (size_t)qtB * 64 * 3072;
  const half8 aA0 = rope8(*(const half8*)qA, pA, g << 2, 0.125f);
  const half8 aA1 = rope8(*(const half8*)(qA + 32), pA, 16 + (g << 2), 0.125f);
  const half8 aB0 = rope8(*(const half8*)qB, pB, g << 2, 0.125f);
  const half8 aB1 = rope8(*(const half8*)(qB + 32), pB, 16 + (g << 2), 0.125f);

  float rmA[4], rlA[4], rmB[4], rlB[4];
  f32x4 oA[4] = {}, oB[4] = {};
#pragma unroll
  for (int r = 0; r < 4; ++r) { rmA[r] = rmB[r] = -3.0e38f; rlA[r] = rlB[r] = 0.f; }

  // pure-DMA staging from pre-swizzled tiles: 2KB per wave per array
  const size_t tbase = ((size_t)((b * 8 + kvh) * 16)) * 4096;
  const f16* kp0 = Kp + tbase + w * 1024 + (l << 3);
  const f16* vp0 = Vt + tbase + w * 1024 + (l << 3);
  auto stage = [&](int buf, int kt) {
    const f16* kp = kp0 + (size_t)kt * 4096;
    const f16* vp = vp0 + (size_t)kt * 4096;
    f16* kl = (f16*)(KsB[buf] + w * 2048);
    f16* vl = (f16*)(VtB[buf] + w * 2048);
    gload_lds16(kp, kl);
    gload_lds16(kp + 512, kl + 512);
    gload_lds16(vp, vl);
    gload_lds16(vp + 512, vl + 512);
  };

  auto compute = [&](int buf, const half8& a0, const half8& a1, float* rm, float* rl,
                     f32x4* o, int qt, int kt) {
    f32x4 s4[4] = {};
#pragma unroll
    for (int j = 0; j < 4; ++j) {
      const half8 bk0 = *(const half8*)KS(buf, j * 16 + fr, g);
      const half8 bk1 = *(const half8*)KS(buf, j * 16 + fr, 4 + g);
      s4[j] = __builtin_amdgcn_mfma_f32_16x16x32_f16(a0, bk0, s4[j], 0, 0, 0);
      s4[j] = __builtin_amdgcn_mfma_f32_16x16x32_f16(a1, bk1, s4[j], 0, 0, 0);
    }
    if (kt == qt) {
      const int qrow0 = qt * 64 + w * 16 + orow;
#pragma unroll
      for (int j = 0; j < 4; ++j) {
        const int col = kt * 64 + j * 16 + fr;
#pragma unroll
        for (int r = 0; r < 4; ++r)
          if (col > qrow0 + r) s4[j][r] = -1.0e30f;
      }
    }
#pragma unroll
    for (int r = 0; r < 4; ++r) {
      float mx = fmaxf(fmaxf(s4[0][r], s4[1][r]), fmaxf(s4[2][r], s4[3][r]));
#pragma unroll
      for (int off = 8; off >= 1; off >>= 1) mx = fmaxf(mx, __shfl_xor(mx, off));
      const float mn = fmaxf(rm[r], mx);
      const float sf = __expf(rm[r] - mn);
      rl[r] *= sf;
      o[0][r] *= sf; o[1][r] *= sf; o[2][r] *= sf; o[3][r] *= sf;
      rm[r] = mn;
    }
    float ps[4] = {0.f, 0.f, 0.f, 0.f};
#pragma unroll
    for (int j = 0; j < 4; ++j)
#pragma unroll
      for (int r = 0; r < 4; ++r) {
        const float p = __expf(s4[j][r] - rm[r]);
        ps[r] += p;
        Ps[w][orow + r][j * 16 + fr] = (f16)p;
      }
#pragma unroll
    for (int r = 0; r < 4; ++r) {
      float t = ps[r];
#pragma unroll
      for (int off = 8; off >= 1; off >>= 1) t += __shfl_xor(t, off);
      rl[r] += t;
    }
#pragma unroll
    for (int kv2 = 0; kv2 < 2; ++kv2) {
      const half8 ap = *(const half8*)&Ps[w][fr][kv2 * 32 + (g << 3)];
#pragma unroll
      for (int j = 0; j < 4; ++j) {
        const half8 bv = *(const half8*)VT(buf, j * 16 + fr, kv2 * 4 + g);
        o[j] = __builtin_amdgcn_mfma_f32_16x16x32_f16(ap, bv, o[j], 0, 0, 0);
      }
    }
  };

  stage(0, 0);
  __syncthreads();
  for (int kt = 0; kt <= qtB; ++kt) {
    const int buf = kt & 1;
    if (kt < qtB) stage(buf ^ 1, kt + 1);  // prefetch next tile (DMA)
    if (kt <= qtA) compute(buf, aA0, aA1, rmA, rlA, oA, qtA, kt);
    compute(buf, aB0, aB1, rmB, rlB, oB, qtB, kt);
    __syncthreads();
  }

#pragma unroll
  for (int j = 0; j < 4; ++j)
#pragma unroll
    for (int r = 0; r < 4; ++r) {
      const int rowA = qtA * 64 + w * 16 + orow + r;
      const int rowB = qtB * 64 + w * 16 + orow + r;
      const int col = h * 64 + j * 16 + fr;
      O[(size_t)(b * 1024 + rowA) * 2048 + col] = (f16)(oA[j][r] / rlA[r]);
      O[(size_t)(b * 1024 + rowB) * 2048 + col] = (f16)(oB[j][r] / rlB[r]);
    }
}

// ---------------------------------------------------------------- launch
extern "C" void kernel_launch(void* const* d_in, const int* in_sizes, int n_in,
                              void* d_out, int out_size, void* d_ws, size_t ws_size,
                              hipStream_t stream) {
  const float* X = (const float*)d_in[0];
  const int* tokpos = (const int*)d_in[1];
  const float* qw = (const float*)d_in[2];
  const float* kw = (const float*)d_in[3];
  const float* vw = (const float*)d_in[4];
  const float* ow = (const float*)d_in[5];

  constexpr int B = 2, S = 1024, D = 2048, DKV = 512, H = 32;
  constexpr int M = B * S;           // 2048
  constexpr int NQKV = D + 2 * DKV;  // 3072

  char* ws = (char*)d_ws;
  f16* Xh   = (f16*)(ws);                    //  8 MiB: X f16 (dead after QKV GEMM)
  f16* QKVW = (f16*)(ws + (8u << 20));       // 12 MiB: concat [q_w; k_w; v_w]
  f16* owh  = (f16*)(ws + (20u << 20));      //  8 MiB
  f16* QKVc = (f16*)(ws + (28u << 20));      // 12 MiB: [2048][3072] fused Q|K|V
  f16* Ah   = (f16*)(ws + (40u << 20));      //  8 MiB: attention output
  // Kp/Vt reuse Xh's space (X is consumed by the QKV GEMM before repack runs)
  f16* Kp   = (f16*)(ws);                    //  2 MiB: roped, tiled, pre-swizzled K
  f16* Vt   = (f16*)(ws + (2u << 20));       //  2 MiB: transposed, pre-swizzled V

  cvt_all<<<2048, 256, 0, stream>>>(X, Xh, M * D,
                                    qw, QKVW, D * D,
                                    kw, QKVW + (size_t)D * D, DKV * D,
                                    vw, QKVW + (size_t)(D + DKV) * D, DKV * D,
                                    ow, owh, D * D);

  // fused QKV projection: [2048][3072] = X @ [q_w;k_w;v_w]^T
  gemm_bt<0><<<dim3(NQKV / 128, M / 64), 256, 0, stream>>>(Xh, QKVW, QKVc, M, NQKV, D);

  // one-time K-rope + V-transpose into pre-swizzled tiles
  repack_kv<<<dim3(16, 8, 2), 256, 0, stream>>>(QKVc, tokpos, Kp, Vt);

  // causal GQA attention (512 blocks)
  attn_fwd<<<dim3(8, H, B), 256, 0, stream>>>(QKVc, Kp, Vt, tokpos, Ah);

  // output projection -> fp32 d_out
  gemm_bt<1><<<dim3(D / 128, M / 64), 256, 0, stream>>>(Ah, owh, d_out, M, D, D);
}

// Round 5
// 137.508 us; speedup vs baseline: 2.2937x; 1.0193x over previous
//
#include <hip/hip_runtime.h>

typedef _Float16 f16;
typedef _Float16 half8 __attribute__((ext_vector_type(8), may_alias));
typedef _Float16 half4 __attribute__((ext_vector_type(4), may_alias));
typedef float f32x4 __attribute__((ext_vector_type(4), may_alias));

#define ROPE_KF -0.41524101186092027f  // -log2(10000)/32

// ---------------------------------------------------------------- helpers
__device__ __forceinline__ void gload_lds16(const f16* g, f16* lds) {
  __builtin_amdgcn_global_load_lds(
      (const __attribute__((address_space(1))) void*)g,
      (__attribute__((address_space(3))) void*)lds, 16, 0, 0);
}

template <int N>
__device__ __forceinline__ void waitcnt_vm() {
  if constexpr (N == 0) asm volatile("s_waitcnt vmcnt(0)" ::: "memory");
  else if constexpr (N == 3) asm volatile("s_waitcnt vmcnt(3)" ::: "memory");
  else if constexpr (N == 4) asm volatile("s_waitcnt vmcnt(4)" ::: "memory");
}

// rotate 4 interleaved pairs of a half8; i0 = pair index of v[0..1] within head
__device__ __forceinline__ half8 rope8(half8 v, float posf, int i0, float scale) {
  half8 r;
#pragma unroll
  for (int p = 0; p < 4; ++p) {
    const float ang = posf * exp2f(ROPE_KF * (float)(i0 + p));
    float s, c;
    sincosf(ang, &s, &c);
    const float x1 = (float)v[2 * p], x2 = (float)v[2 * p + 1];
    r[2 * p]     = (f16)((x1 * c - x2 * s) * scale);
    r[2 * p + 1] = (f16)((x1 * s + x2 * c) * scale);
  }
  return r;
}

// ---------------------------------------------------------------- fused fp32 -> f16 (5 segments)
__global__ __launch_bounds__(256) void cvt_all(const float* __restrict__ s0, f16* __restrict__ d0, int n0,
                                               const float* __restrict__ s1, f16* __restrict__ d1, int n1,
                                               const float* __restrict__ s2, f16* __restrict__ d2, int n2,
                                               const float* __restrict__ s3, f16* __restrict__ d3, int n3,
                                               const float* __restrict__ s4, f16* __restrict__ d4, int n4) {
  const int step = gridDim.x * blockDim.x * 4;
  const int base = (blockIdx.x * blockDim.x + threadIdx.x) * 4;
  auto go = [&](const float* s, f16* d, int n) {
    for (int i = base; i < n; i += step) {
      float4 v = *(const float4*)(s + i);
      half4 h;
      h[0] = (f16)v.x; h[1] = (f16)v.y; h[2] = (f16)v.z; h[3] = (f16)v.w;
      *(half4*)(d + i) = h;
    }
  };
  go(s0, d0, n0); go(s1, d1, n1); go(s2, d2, n2); go(s3, d3, n3); go(s4, d4, n4);
}

// ---------------------------------------------------------------- GEMM: C = A @ B^T
// A[M][K], B[N][K] f16 row-major; C f32 (OUT_F32=1) or f16 (OUT_F32=0).
// Block tile BM x 128, BK=32. BM=128: 4 waves as 2x2, wave=64x64 (16 MFMA/step).
// BM=64: 4 waves as 1x4, wave=64x32 (8 MFMA/step).
// Depth-2 staging pipeline with counted vmcnt (never drain to 0 in the loop).
template <int OUT_F32, int BM>
__global__ __launch_bounds__(256, 2) void gemm_bt(const f16* __restrict__ A,
                                                  const f16* __restrict__ B,
                                                  void* __restrict__ Cv,
                                                  int M, int N, int K) {
  constexpr int NJ = (BM == 128) ? 4 : 2;   // B frags per wave
  constexpr int ACH = BM / 64;              // A gload chunks per wave
  constexpr int LPS = ACH + 2;              // gloads per wave per stage

  __shared__ alignas(16) f16 As[2][BM][32];
  __shared__ alignas(16) f16 Bs[2][128][32];
  const int tid = threadIdx.x;
  const int w = tid >> 6, l = tid & 63;
  const int m0 = blockIdx.y * BM, n0 = blockIdx.x << 7;
  const int fr = l & 15;
  const int fkz = (((l >> 4) ^ ((fr >> 1) & 3)) << 3);  // swizzled k-slot
  const int wr = (BM == 128) ? ((w >> 1) << 6) : 0;
  const int wc = (BM == 128) ? ((w & 1) << 6) : (w << 5);
  const int srow = l >> 2;
  const int scol = (((l & 3) ^ ((l >> 3) & 3)) << 3);   // pre-swizzled global slot

  const f16* ga = A + (size_t)(m0 + srow) * K + scol;
  const f16* gb = B + (size_t)(n0 + srow) * K + scol;

  auto stage = [&](int buf, int t) {
    const int k0 = t << 5;
#pragma unroll
    for (int c = 0; c < ACH; ++c) {
      const int rb = (w * ACH + c) << 4;
      gload_lds16(ga + (size_t)rb * K + k0, &As[buf][rb][0]);
    }
#pragma unroll
    for (int c = 0; c < 2; ++c) {
      const int rb = (w * 2 + c) << 4;
      gload_lds16(gb + (size_t)rb * K + k0, &Bs[buf][rb][0]);
    }
  };

  f32x4 acc[4][NJ] = {};

  const int nk = K >> 5;
  stage(0, 0);
  stage(1, 1);
  for (int t = 0; t < nk; ++t) {
    const int buf = t & 1;
    if (t + 1 < nk) waitcnt_vm<LPS>();  // stage(t) landed; stage(t+1) in flight
    else waitcnt_vm<0>();
    __builtin_amdgcn_s_barrier();
    __builtin_amdgcn_sched_barrier(0);  // no ds_read hoisted above the barrier
    half8 af[4], bf[NJ];
#pragma unroll
    for (int i = 0; i < 4; ++i) af[i] = *(const half8*)&As[buf][wr + i * 16 + fr][fkz];
#pragma unroll
    for (int j = 0; j < NJ; ++j) bf[j] = *(const half8*)&Bs[buf][wc + j * 16 + fr][fkz];
#pragma unroll
    for (int i = 0; i < 4; ++i)
#pragma unroll
      for (int j = 0; j < NJ; ++j)
        acc[i][j] = __builtin_amdgcn_mfma_f32_16x16x32_f16(af[i], bf[j], acc[i][j], 0, 0, 0);
    __builtin_amdgcn_sched_barrier(0);  // all reads of buf consumed above
    __builtin_amdgcn_s_barrier();
    if (t + 2 < nk) stage(buf, t + 2);  // overwrite buf (everyone is done with it)
  }

  const int orow = (l >> 4) << 2;
#pragma unroll
  for (int i = 0; i < 4; ++i) {
#pragma unroll
    for (int j = 0; j < NJ; ++j) {
      const int col = n0 + wc + j * 16 + fr;
#pragma unroll
      for (int r = 0; r < 4; ++r) {
        const size_t idx = (size_t)(m0 + wr + i * 16 + orow + r) * N + col;
        if (OUT_F32) ((float*)Cv)[idx] = acc[i][j][r];
        else ((f16*)Cv)[idx] = (f16)acc[i][j][r];
      }
    }
  }
}

// ---------------------------------------------------------------- K/V repack
// One-time: rope K, transpose V, write both per-(b,kvh,kt) as 8KB tiles in the
// EXACT pre-swizzled byte order attention's LDS consumes (linear DMA copy there).
__global__ __launch_bounds__(256) void repack_kv(const f16* __restrict__ QKV,
                                                 const int* __restrict__ pos,
                                                 f16* __restrict__ Kp,
                                                 f16* __restrict__ Vt) {
  const int kt = blockIdx.x, kvh = blockIdx.y, b = blockIdx.z;
  const int tid = threadIdx.x;
  __shared__ f16 vs[64][72];
  const size_t tile = ((size_t)((b * 8 + kvh) * 16 + kt)) * 4096;
  const f16* kbase = QKV + 2048 + kvh * 64;
  const f16* vbase = QKV + 2560 + kvh * 64;
#pragma unroll
  for (int p = 0; p < 2; ++p) {
    const int c = tid + p * 256;
    const int row = c >> 3, slot = c & 7;
    const size_t grow = (size_t)(b * 1024 + kt * 64 + row) * 3072;
    half8 kk = *(const half8*)(kbase + grow + slot * 8);
    kk = rope8(kk, (float)pos[kt * 64 + row], slot << 2, 1.0f);
    *(half8*)(Kp + tile + row * 64 + ((slot ^ (row & 7)) << 3)) = kk;
    *(half8*)&vs[row][slot * 8] = *(const half8*)(vbase + grow + slot * 8);
  }
  __syncthreads();
#pragma unroll
  for (int p = 0; p < 2; ++p) {
    const int c = tid + p * 256;
    const int d = c >> 3, oct = c & 7;
    half8 vv;
#pragma unroll
    for (int m = 0; m < 8; ++m) vv[m] = vs[oct * 8 + m][d];
    *(half8*)(Vt + tile + d * 64 + ((oct ^ (d & 7)) << 3)) = vv;
  }
}

// ---------------------------------------------------------------- causal GQA attention v5
// Q from QKV (roped in-register once, +0.125 scale); K/V from pre-swizzled
// tiles via pure-DMA depth-2 counted-vmcnt staging. Paired q-tiles (qt, 15-qt).
__global__ __launch_bounds__(256) void attn_fwd(const f16* __restrict__ QKV,
                                                const f16* __restrict__ Kp,
                                                const f16* __restrict__ Vt,
                                                const int* __restrict__ pos,
                                                f16* __restrict__ O) {
  const int flat = blockIdx.x + (blockIdx.y << 3) + (blockIdx.z << 8);
  const int rmid = ((flat & 7) << 6) + (flat >> 3);
  const int pr = rmid & 7, h = (rmid >> 3) & 31, b = rmid >> 8;
  const int kvh = h >> 2;
  const int tid = threadIdx.x, w = tid >> 6, l = tid & 63;
  const int fr = l & 15, g = l >> 4;
  const int orow = g << 2;
  const int qtA = pr, qtB = 15 - pr;

  __shared__ alignas(16) char KsB[2][8192];
  __shared__ alignas(16) char VtB[2][8192];
  __shared__ alignas(16) f16 Ps[4][16][72];

  auto KS = [&](int buf, int row, int slot) -> f16* {
    return (f16*)(KsB[buf] + row * 128 + ((slot ^ (row & 7)) << 4));
  };
  auto VT = [&](int buf, int d, int oct) -> f16* {
    return (f16*)(VtB[buf] + d * 128 + ((oct ^ (d & 7)) << 4));
  };

  // Q fragments (two q-tiles) in registers, roped + scaled
  const int sA = qtA * 64 + w * 16 + fr, sB = qtB * 64 + w * 16 + fr;
  const float pA = (float)pos[sA], pB = (float)pos[sB];
  const size_t qoff = (size_t)(b * 1024 + w * 16 + fr) * 3072 + h * 64 + (g << 3);
  const f16* qA = QKV + qoff + (size_t)qtA * 64 * 3072;
  const f16* qB = QKV + qoff + (size_t)qtB * 64 * 3072;
  const half8 aA0 = rope8(*(const half8*)qA, pA, g << 2, 0.125f);
  const half8 aA1 = rope8(*(const half8*)(qA + 32), pA, 16 + (g << 2), 0.125f);
  const half8 aB0 = rope8(*(const half8*)qB, pB, g << 2, 0.125f);
  const half8 aB1 = rope8(*(const half8*)(qB + 32), pB, 16 + (g << 2), 0.125f);

  float rmA[4], rlA[4], rmB[4], rlB[4];
  f32x4 oA[4] = {}, oB[4] = {};
#pragma unroll
  for (int r = 0; r < 4; ++r) { rmA[r] = rmB[r] = -3.0e38f; rlA[r] = rlB[r] = 0.f; }

  // pure-DMA staging from pre-swizzled tiles: 2KB per wave per array
  const size_t tbase = ((size_t)((b * 8 + kvh) * 16)) * 4096;
  const f16* kp0 = Kp + tbase + w * 1024 + (l << 3);
  const f16* vp0 = Vt + tbase + w * 1024 + (l << 3);
  auto stage = [&](int buf, int kt) {
    const f16* kp = kp0 + (size_t)kt * 4096;
    const f16* vp = vp0 + (size_t)kt * 4096;
    f16* kl = (f16*)(KsB[buf] + w * 2048);
    f16* vl = (f16*)(VtB[buf] + w * 2048);
    gload_lds16(kp, kl);
    gload_lds16(kp + 512, kl + 512);
    gload_lds16(vp, vl);
    gload_lds16(vp + 512, vl + 512);
  };

  auto compute = [&](int buf, const half8& a0, const half8& a1, float* rm, float* rl,
                     f32x4* o, int qt, int kt) {
    f32x4 s4[4] = {};
#pragma unroll
    for (int j = 0; j < 4; ++j) {
      const half8 bk0 = *(const half8*)KS(buf, j * 16 + fr, g);
      const half8 bk1 = *(const half8*)KS(buf, j * 16 + fr, 4 + g);
      s4[j] = __builtin_amdgcn_mfma_f32_16x16x32_f16(a0, bk0, s4[j], 0, 0, 0);
      s4[j] = __builtin_amdgcn_mfma_f32_16x16x32_f16(a1, bk1, s4[j], 0, 0, 0);
    }
    if (kt == qt) {
      const int qrow0 = qt * 64 + w * 16 + orow;
#pragma unroll
      for (int j = 0; j < 4; ++j) {
        const int col = kt * 64 + j * 16 + fr;
#pragma unroll
        for (int r = 0; r < 4; ++r)
          if (col > qrow0 + r) s4[j][r] = -1.0e30f;
      }
    }
#pragma unroll
    for (int r = 0; r < 4; ++r) {
      float mx = fmaxf(fmaxf(s4[0][r], s4[1][r]), fmaxf(s4[2][r], s4[3][r]));
#pragma unroll
      for (int off = 8; off >= 1; off >>= 1) mx = fmaxf(mx, __shfl_xor(mx, off));
      const float mn = fmaxf(rm[r], mx);
      const float sf = __expf(rm[r] - mn);
      rl[r] *= sf;
      o[0][r] *= sf; o[1][r] *= sf; o[2][r] *= sf; o[3][r] *= sf;
      rm[r] = mn;
    }
    float ps[4] = {0.f, 0.f, 0.f, 0.f};
#pragma unroll
    for (int j = 0; j < 4; ++j)
#pragma unroll
      for (int r = 0; r < 4; ++r) {
        const float p = __expf(s4[j][r] - rm[r]);
        ps[r] += p;
        Ps[w][orow + r][j * 16 + fr] = (f16)p;
      }
#pragma unroll
    for (int r = 0; r < 4; ++r) {
      float t = ps[r];
#pragma unroll
      for (int off = 8; off >= 1; off >>= 1) t += __shfl_xor(t, off);
      rl[r] += t;
    }
#pragma unroll
    for (int kv2 = 0; kv2 < 2; ++kv2) {
      const half8 ap = *(const half8*)&Ps[w][fr][kv2 * 32 + (g << 3)];
#pragma unroll
      for (int j = 0; j < 4; ++j) {
        const half8 bv = *(const half8*)VT(buf, j * 16 + fr, kv2 * 4 + g);
        o[j] = __builtin_amdgcn_mfma_f32_16x16x32_f16(ap, bv, o[j], 0, 0, 0);
      }
    }
  };

  stage(0, 0);
  stage(1, 1);  // qtB >= 8 always, so tile 1 exists
  for (int kt = 0; kt <= qtB; ++kt) {
    const int buf = kt & 1;
    if (kt < qtB) waitcnt_vm<4>();  // stage(kt) landed; stage(kt+1) in flight
    else waitcnt_vm<0>();
    __builtin_amdgcn_s_barrier();
    __builtin_amdgcn_sched_barrier(0);
    if (kt <= qtA) compute(buf, aA0, aA1, rmA, rlA, oA, qtA, kt);
    compute(buf, aB0, aB1, rmB, rlB, oB, qtB, kt);
    __builtin_amdgcn_sched_barrier(0);
    __builtin_amdgcn_s_barrier();
    if (kt + 2 <= qtB) stage(buf, kt + 2);
  }

#pragma unroll
  for (int j = 0; j < 4; ++j)
#pragma unroll
    for (int r = 0; r < 4; ++r) {
      const int rowA = qtA * 64 + w * 16 + orow + r;
      const int rowB = qtB * 64 + w * 16 + orow + r;
      const int col = h * 64 + j * 16 + fr;
      O[(size_t)(b * 1024 + rowA) * 2048 + col] = (f16)(oA[j][r] / rlA[r]);
      O[(size_t)(b * 1024 + rowB) * 2048 + col] = (f16)(oB[j][r] / rlB[r]);
    }
}

// ---------------------------------------------------------------- launch
extern "C" void kernel_launch(void* const* d_in, const int* in_sizes, int n_in,
                              void* d_out, int out_size, void* d_ws, size_t ws_size,
                              hipStream_t stream) {
  const float* X = (const float*)d_in[0];
  const int* tokpos = (const int*)d_in[1];
  const float* qw = (const float*)d_in[2];
  const float* kw = (const float*)d_in[3];
  const float* vw = (const float*)d_in[4];
  const float* ow = (const float*)d_in[5];

  constexpr int B = 2, S = 1024, D = 2048, DKV = 512, H = 32;
  constexpr int M = B * S;           // 2048
  constexpr int NQKV = D + 2 * DKV;  // 3072

  char* ws = (char*)d_ws;
  f16* Xh   = (f16*)(ws);                    //  8 MiB: X f16 (dead after QKV GEMM)
  f16* QKVW = (f16*)(ws + (8u << 20));       // 12 MiB: concat [q_w; k_w; v_w]
  f16* owh  = (f16*)(ws + (20u << 20));      //  8 MiB
  f16* QKVc = (f16*)(ws + (28u << 20));      // 12 MiB: [2048][3072] fused Q|K|V
  f16* Ah   = (f16*)(ws + (40u << 20));      //  8 MiB: attention output
  // Kp/Vt reuse Xh's space (X is consumed by the QKV GEMM before repack runs)
  f16* Kp   = (f16*)(ws);                    //  2 MiB: roped, tiled, pre-swizzled K
  f16* Vt   = (f16*)(ws + (2u << 20));       //  2 MiB: transposed, pre-swizzled V

  cvt_all<<<2048, 256, 0, stream>>>(X, Xh, M * D,
                                    qw, QKVW, D * D,
                                    kw, QKVW + (size_t)D * D, DKV * D,
                                    vw, QKVW + (size_t)(D + DKV) * D, DKV * D,
                                    ow, owh, D * D);

  // fused QKV projection: [2048][3072] = X @ [q_w;k_w;v_w]^T  (128x128 tiles)
  gemm_bt<0, 128><<<dim3(NQKV / 128, M / 128), 256, 0, stream>>>(Xh, QKVW, QKVc, M, NQKV, D);

  // one-time K-rope + V-transpose into pre-swizzled tiles
  repack_kv<<<dim3(16, 8, 2), 256, 0, stream>>>(QKVc, tokpos, Kp, Vt);

  // causal GQA attention (512 blocks)
  attn_fwd<<<dim3(8, H, B), 256, 0, stream>>>(QKVc, Kp, Vt, tokpos, Ah);

  // output projection -> fp32 d_out (64x128 tiles: 512 blocks, perfect balance)
  gemm_bt<1, 64><<<dim3(D / 128, M / 64), 256, 0, stream>>>(Ah, owh, d_out, M, D, D);
}